// Round 7
// baseline (122.872 us; speedup 1.0000x reference)
//
#include <hip/hip_runtime.h>
#include <hip/hip_bf16.h>
#include <math.h>

#define NROWS 8192
#define DDIM  128
#define JCHUNKS 16
#define JPER  (NROWS / JCHUNKS)        // 512 cols per chunk
#define STAGE_COLS 64
#define NSTAGES (JPER / STAGE_COLS)    // 8
#define ROWS_PER_BLOCK 128             // 4 waves x 32 rows
#define GRIDX (NROWS / ROWS_PER_BLOCK) // 64
#define NBUCK 1024

#define AS1 __attribute__((address_space(1)))
#define AS3 __attribute__((address_space(3)))

typedef __attribute__((ext_vector_type(8))) short bf16x8;  // 8 bf16 = 4 VGPRs
typedef __attribute__((ext_vector_type(4))) float f32x4;
typedef __attribute__((ext_vector_type(2))) float f32x2;

// degree-4 poly for e^(c-1) on c in [-1.05, 1.05] (Chebyshev, abs err ~2e-4)
#define PB0 0.3678959f
#define PB1 0.3668905f
#define PB2 0.1836441f
#define PB3 0.0652423f
#define PB4 0.0161110f

__device__ inline f32x2 expcm1(f32x2 c) {   // ~ e^(c-1)
  f32x2 e = {PB4, PB4};
  e = e * c + (f32x2){PB3, PB3};
  e = e * c + (f32x2){PB2, PB2};
  e = e * c + (f32x2){PB1, PB1};
  e = e * c + (f32x2){PB0, PB0};
  return e;
}

// ---------------- kernel 0: bucket-sort indices by target ----------------
// outputs: pi (permutation), tps (t' = t + 10*sign(t), sorted order),
//          jmm[k] = (min, max) of t' over sorted cols [16k, 16k+16)
__global__ __launch_bounds__(1024) void sort_kernel(
    const float* __restrict__ targets,
    int* __restrict__ pi, float* __restrict__ tps, float2* __restrict__ jmm) {
  __shared__ int hist[NBUCK];
  __shared__ int scanb[NBUCK];
  __shared__ float tloc[NROWS];
  const int tid = threadIdx.x;
  hist[tid] = 0;
  __syncthreads();
  #pragma unroll
  for (int r = 0; r < NROWS / 1024; ++r) {
    float t = targets[r * 1024 + tid];
    int b = (int)((t + 1.0f) * (NBUCK / 2));
    b = min(max(b, 0), NBUCK - 1);
    atomicAdd(&hist[b], 1);
  }
  __syncthreads();
  int own = hist[tid];
  scanb[tid] = own;
  __syncthreads();
  for (int d = 1; d < NBUCK; d <<= 1) {   // inclusive Hillis-Steele scan
    int nv = scanb[tid];
    if (tid >= d) nv += scanb[tid - d];
    __syncthreads();
    scanb[tid] = nv;
    __syncthreads();
  }
  hist[tid] = scanb[tid] - own;           // exclusive offset, reused as cursor
  __syncthreads();
  #pragma unroll
  for (int r = 0; r < NROWS / 1024; ++r) {
    int i = r * 1024 + tid;
    float t = targets[i];
    int b = (int)((t + 1.0f) * (NBUCK / 2));
    b = min(max(b, 0), NBUCK - 1);
    int pos = atomicAdd(&hist[b], 1);
    pi[pos] = i;
    tloc[pos] = t + (t > 0.0f ? 10.0f : -10.0f);
  }
  __syncthreads();
  #pragma unroll
  for (int r = 0; r < NROWS / 1024; ++r) {
    int i = r * 1024 + tid;
    tps[i] = tloc[i];
  }
  for (int k = tid; k < NROWS / 16; k += 1024) {
    float mn = tloc[16 * k], mx = mn;
    #pragma unroll
    for (int u = 1; u < 16; ++u) {
      float x = tloc[16 * k + u];
      mn = fminf(mn, x); mx = fmaxf(mx, x);
    }
    jmm[k] = make_float2(mn, mx);
  }
}

// ---------------- kernel 1: L2 row-normalize -> bf16 (also zeroes out[0]) ----------------
__global__ __launch_bounds__(256) void norm_kernel(
    const float* __restrict__ f1, const float* __restrict__ f2,
    __hip_bfloat16* __restrict__ f1b, __hip_bfloat16* __restrict__ f2b,
    float* __restrict__ out) {
  if (blockIdx.x == 0 && threadIdx.x == 0) out[0] = 0.0f;
  int t = threadIdx.x;
  int rloc = t >> 5;
  int l = t & 31;
  int b = blockIdx.x;
  int half = (b >= NROWS / 8) ? 1 : 0;
  int row = (b - half * (NROWS / 8)) * 8 + rloc;
  const float* src = half ? f2 : f1;
  __hip_bfloat16* dst = half ? f2b : f1b;

  float4 v = ((const float4*)src)[row * (DDIM / 4) + l];
  float s = v.x * v.x + v.y * v.y + v.z * v.z + v.w * v.w;
  #pragma unroll
  for (int off = 1; off < 32; off <<= 1) s += __shfl_xor(s, off, 64);
  float inv = 1.0f / fmaxf(sqrtf(s), 1e-12f);
  __hip_bfloat16 hv[4];
  hv[0] = __float2bfloat16(v.x * inv);
  hv[1] = __float2bfloat16(v.y * inv);
  hv[2] = __float2bfloat16(v.z * inv);
  hv[3] = __float2bfloat16(v.w * inv);
  *(ushort4*)&dst[(size_t)row * DDIM + l * 4] = *(ushort4*)hv;
}

// ---------------- kernel 2: MFMA cos grid (sorted index space), classified epilogue ----------------
// partials[(row*JCHUNKS + chunk)*4 + {Z, Zp, Cp, Np}]
__global__ __launch_bounds__(256, 4) void stats_kernel(
    const __hip_bfloat16* __restrict__ f1b,
    const __hip_bfloat16* __restrict__ f2b,
    const int* __restrict__ pi,
    const float* __restrict__ tps,
    const float2* __restrict__ jmm,
    float* __restrict__ partials) {
  __shared__ __align__(16) char lds0[STAGE_COLS * 256];   // 16 KB
  __shared__ __align__(16) char lds1[STAGE_COLS * 256];   // 16 KB
  __shared__ __align__(16) float tsh[JPER];               // 2 KB  (t', sorted)
  __shared__ __align__(16) float jsh[(JPER / 16) * 2];    // 256 B (tile min/max)

  const int chunk = blockIdx.y;
  const int i0 = blockIdx.x * ROWS_PER_BLOCK;
  const int w    = threadIdx.x >> 6;
  const int lane = threadIdx.x & 63;
  const int p15  = lane & 15;
  const int rl4  = lane >> 4;
  const int rbase = i0 + w * 32;

  // ---- A fragments via permutation gather (rows in sorted index space) ----
  int ar0 = pi[rbase + p15];
  int ar1 = pi[rbase + 16 + p15];
  bf16x8 afrag[2][4];
  #pragma unroll
  for (int ks = 0; ks < 4; ++ks) {
    afrag[0][ks] = *(const bf16x8*)&f1b[(size_t)ar0 * DDIM + rl4 * 8 + ks * 32];
    afrag[1][ks] = *(const bf16x8*)&f1b[(size_t)ar1 * DDIM + rl4 * 8 + ks * 32];
  }

  // lane's C rows (sorted order): comp0 = quad*4+rr, comp1 = 16+quad*4+rr
  f32x2 tip2[4];
  #pragma unroll
  for (int rr = 0; rr < 4; ++rr) {
    tip2[rr][0] = tps[rbase + rl4 * 4 + rr];
    tip2[rr][1] = tps[rbase + 16 + rl4 * 4 + rr];
  }
  // wave-wide row t' range
  float twmin = tip2[0][0], twmax = tip2[0][0];
  #pragma unroll
  for (int rr = 0; rr < 4; ++rr) {
    twmin = fminf(twmin, fminf(tip2[rr][0], tip2[rr][1]));
    twmax = fmaxf(twmax, fmaxf(tip2[rr][0], tip2[rr][1]));
  }
  #pragma unroll
  for (int off = 1; off < 64; off <<= 1) {
    twmin = fminf(twmin, __shfl_xor(twmin, off, 64));
    twmax = fmaxf(twmax, __shfl_xor(twmax, off, 64));
  }

  f32x2 Z2[4]  = {{0,0},{0,0},{0,0},{0,0}};
  f32x2 Zp2[4] = {{0,0},{0,0},{0,0},{0,0}};
  f32x2 Cp2[4] = {{0,0},{0,0},{0,0},{0,0}};
  f32x2 Np2[4] = {{0,0},{0,0},{0,0},{0,0}};
  float posTiles = 0.0f;

  const int jb0 = chunk * JPER;
  const int rloc0 = w * 16 + rl4;                 // + q*4 below

  // prologue DMAs: t' chunk, tile min/max, B stage 0 (gathered via pi)
  #pragma unroll
  for (int rnd = 0; rnd < 2; ++rnd)
    __builtin_amdgcn_global_load_lds(
        (const AS1 void*)(tps + jb0 + rnd * 256 + w * 64 + lane),
        (AS3 void*)(&tsh[rnd * 256 + w * 64]), 4, 0, 0);
  if (w == 0)
    __builtin_amdgcn_global_load_lds(
        (const AS1 void*)((const float*)jmm + chunk * 64 + lane),
        (AS3 void*)(&jsh[0]), 4, 0, 0);

  int prow[4];
  #pragma unroll
  for (int q = 0; q < 4; ++q) prow[q] = pi[jb0 + rloc0 + q * 4];
  {
    char* lbase = &lds0[w * 4096];
    #pragma unroll
    for (int q = 0; q < 4; ++q) {
      int c = p15 ^ (q * 4 + rl4);
      __builtin_amdgcn_global_load_lds(
          (const AS1 void*)(f2b + (size_t)prow[q] * DDIM + c * 8),
          (AS3 void*)(lbase + q * 1024), 16, 0, 0);
    }
  }
  #pragma unroll
  for (int q = 0; q < 4; ++q) prow[q] = pi[jb0 + STAGE_COLS + rloc0 + q * 4];

  for (int s = 0; s < NSTAGES; ++s) {
    __syncthreads();   // stage-s DMA complete; other buffer free

    if (s + 1 < NSTAGES) {
      char* lbase = ((s + 1) & 1) ? &lds1[w * 4096] : &lds0[w * 4096];
      #pragma unroll
      for (int q = 0; q < 4; ++q) {
        int c = p15 ^ (q * 4 + rl4);
        __builtin_amdgcn_global_load_lds(
            (const AS1 void*)(f2b + (size_t)prow[q] * DDIM + c * 8),
            (AS3 void*)(lbase + q * 1024), 16, 0, 0);
      }
      if (s + 2 < NSTAGES) {
        #pragma unroll
        for (int q = 0; q < 4; ++q)
          prow[q] = pi[jb0 + (s + 2) * STAGE_COLS + rloc0 + q * 4];
      }
    }

    const char* lb = (s & 1) ? lds1 : lds0;
    #pragma unroll
    for (int ct = 0; ct < 4; ++ct) {
      const int rloc = ct * 16 + p15;
      bf16x8 bfrag[4];
      #pragma unroll
      for (int ks = 0; ks < 4; ++ks)
        bfrag[ks] = *(const bf16x8*)(lb + rloc * 256 + (((rl4 + ks * 4) ^ p15) << 4));

      f32x4 acc0 = {0.f, 0.f, 0.f, 0.f};
      f32x4 acc1 = {0.f, 0.f, 0.f, 0.f};
      #pragma unroll
      for (int ks = 0; ks < 4; ++ks) {
        acc0 = __builtin_amdgcn_mfma_f32_16x16x32_bf16(afrag[0][ks], bfrag[ks], acc0, 0, 0, 0);
        acc1 = __builtin_amdgcn_mfma_f32_16x16x32_bf16(afrag[1][ks], bfrag[ks], acc1, 0, 0, 0);
      }

      const int tl = s * 4 + ct;
      float jmn = jsh[2 * tl], jmx = jsh[2 * tl + 1];
      int uneg = __builtin_amdgcn_readfirstlane(
          ((jmn - twmax > 0.1f) || (twmin - jmx > 0.1f)) ? 1 : 0);
      int upos = __builtin_amdgcn_readfirstlane(
          ((twmax - jmn <= 0.1f) && (jmx - twmin <= 0.1f)) ? 1 : 0);

      if (uneg) {
        #pragma unroll
        for (int rr = 0; rr < 4; ++rr) {
          f32x2 c2 = {acc0[rr], acc1[rr]};
          Z2[rr] += expcm1(c2);
        }
      } else if (upos) {
        posTiles += 1.0f;
        #pragma unroll
        for (int rr = 0; rr < 4; ++rr) {
          f32x2 c2 = {acc0[rr], acc1[rr]};
          f32x2 e2 = expcm1(c2);
          Z2[rr]  += e2;
          Zp2[rr] += e2;
          Cp2[rr] += c2;
        }
      } else {
        float tj = tsh[s * STAGE_COLS + ct * 16 + p15];
        f32x2 tj2 = {tj, tj};
        #pragma unroll
        for (int rr = 0; rr < 4; ++rr) {
          f32x2 c2 = {acc0[rr], acc1[rr]};
          f32x2 d2 = tip2[rr] - tj2;
          bool q0 = __builtin_fabsf(d2[0]) <= 0.1f;
          bool q1 = __builtin_fabsf(d2[1]) <= 0.1f;
          f32x2 m2 = {q0 ? 1.0f : 0.0f, q1 ? 1.0f : 0.0f};
          f32x2 e2 = expcm1(c2);
          Z2[rr]  += e2;
          Zp2[rr] += m2 * e2;
          Cp2[rr] += m2 * c2;
          Np2[rr] += m2;
        }
      }
    }
  }

  #pragma unroll
  for (int rr = 0; rr < 4; ++rr)
    Np2[rr] += (f32x2){posTiles, posTiles};

  // reduce over the 16 lanes (p15) sharing each row
  #pragma unroll
  for (int rr = 0; rr < 4; ++rr) {
    for (int off = 1; off < 16; off <<= 1) {
      Z2[rr][0]  += __shfl_xor(Z2[rr][0],  off, 64);
      Z2[rr][1]  += __shfl_xor(Z2[rr][1],  off, 64);
      Zp2[rr][0] += __shfl_xor(Zp2[rr][0], off, 64);
      Zp2[rr][1] += __shfl_xor(Zp2[rr][1], off, 64);
      Cp2[rr][0] += __shfl_xor(Cp2[rr][0], off, 64);
      Cp2[rr][1] += __shfl_xor(Cp2[rr][1], off, 64);
      Np2[rr][0] += __shfl_xor(Np2[rr][0], off, 64);
      Np2[rr][1] += __shfl_xor(Np2[rr][1], off, 64);
    }
  }
  if (p15 == 0) {
    #pragma unroll
    for (int rs = 0; rs < 2; ++rs)
      #pragma unroll
      for (int rr = 0; rr < 4; ++rr) {
        size_t row = rbase + rs * 16 + rl4 * 4 + rr;
        f32x4 st = {Z2[rr][rs], Zp2[rr][rs], Cp2[rr][rs], Np2[rr][rs]};
        *(f32x4*)&partials[((size_t)row * JCHUNKS + chunk) * 4] = st;
      }
  }
}

// ---------------- kernel 3: per-row loss + global mean (atomic) ----------------
__global__ void finalize_rows(const float* __restrict__ partials,
                              float* __restrict__ out) {
  int r = blockIdx.x * 256 + threadIdx.x;   // grid 32 x 256
  float Z = 0, Zp = 0, Cp = 0, Np = 0;
  for (int ch = 0; ch < JCHUNKS; ++ch) {
    float4 p = *(const float4*)&partials[((size_t)r * JCHUNKS + ch) * 4];
    Z += p.x; Zp += p.y; Cp += p.z; Np += p.w;
  }
  Np *= 16.0f;  // posTiles counted once per lane; 16-lane reduce scaled mixed-path too
  // NOTE: mixed-path Np elements were also scaled by the 16-lane reduction? No:
  // per-lane Np counts that lane's own column hits; the l15 reduction sums 16
  // distinct columns (correct, x1). posTiles was identical across lanes, so the
  // reduction multiplied it by 16 (one tile = 16 columns, also correct, x1).
  Np *= 0.0625f; // undo the lazy x16 above (kept for clarity; net x1)
  float Zn = Z - Zp;
  float nn = (float)NROWS - Np;
  float spos = (1.0f + logf(Z)) - Cp / Np;
  float sneg = Zn / Z - nn * 1e-10f;
  float per_row = spos + sneg / nn;

  float v = per_row;
  for (int off = 32; off; off >>= 1) v += __shfl_xor(v, off, 64);
  __shared__ float wsum[4];
  int lane = threadIdx.x & 63, wid = threadIdx.x >> 6;
  if (lane == 0) wsum[wid] = v;
  __syncthreads();
  if (threadIdx.x == 0)
    atomicAdd(out, (wsum[0] + wsum[1] + wsum[2] + wsum[3]) * (1.0f / (float)NROWS));
}

// ---------------- launch ----------------
extern "C" void kernel_launch(void* const* d_in, const int* in_sizes, int n_in,
                              void* d_out, int out_size, void* d_ws, size_t ws_size,
                              hipStream_t stream) {
  const float* f1  = (const float*)d_in[0];
  const float* f2  = (const float*)d_in[1];
  const float* tgt = (const float*)d_in[2];
  float* out = (float*)d_out;

  char* ws = (char*)d_ws;
  __hip_bfloat16* f1b = (__hip_bfloat16*)ws;                          // 2 MB
  __hip_bfloat16* f2b = (__hip_bfloat16*)(ws + (size_t)NROWS * DDIM * 2);
  float* partials = (float*)(ws + (size_t)NROWS * DDIM * 4);          // 2 MB
  int*   pi  = (int*)(ws + (size_t)NROWS * DDIM * 4 + (size_t)NROWS * JCHUNKS * 16);
  float* tps = (float*)((char*)pi + NROWS * 4);
  float2* jmm = (float2*)((char*)tps + NROWS * 4);

  sort_kernel<<<1, 1024, 0, stream>>>(tgt, pi, tps, jmm);
  norm_kernel<<<2 * (NROWS / 8), 256, 0, stream>>>(f1, f2, f1b, f2b, out);
  dim3 g2(GRIDX, JCHUNKS);
  stats_kernel<<<g2, 256, 0, stream>>>(f1b, f2b, pi, tps, jmm, partials);
  finalize_rows<<<NROWS / 256, 256, 0, stream>>>(partials, out);
}

// Round 8
// 113.847 us; speedup vs baseline: 1.0793x; 1.0793x over previous
//
#include <hip/hip_runtime.h>
#include <hip/hip_bf16.h>
#include <math.h>

#define NROWS 8192
#define DDIM  128
#define JCHUNKS 16
#define JPER  (NROWS / JCHUNKS)        // 512 cols per chunk
#define STAGE_COLS 64
#define NSTAGES (JPER / STAGE_COLS)    // 8
#define ROWS_PER_BLOCK 128             // 4 waves x 32 rows
#define GRIDX (NROWS / ROWS_PER_BLOCK) // 64
#define NBUCK 1024

#define AS1 __attribute__((address_space(1)))
#define AS3 __attribute__((address_space(3)))

typedef __attribute__((ext_vector_type(8))) short bf16x8;  // 8 bf16 = 4 VGPRs
typedef __attribute__((ext_vector_type(4))) float f32x4;
typedef __attribute__((ext_vector_type(2))) float f32x2;

// degree-4 poly for e^(c-1) on c in [-1.05, 1.05] (Chebyshev, abs err ~2e-4)
#define PB0 0.3678959f
#define PB1 0.3668905f
#define PB2 0.1836441f
#define PB3 0.0652423f
#define PB4 0.0161110f

__device__ inline f32x2 expcm1(f32x2 c) {   // ~ e^(c-1)
  f32x2 e = {PB4, PB4};
  e = e * c + (f32x2){PB3, PB3};
  e = e * c + (f32x2){PB2, PB2};
  e = e * c + (f32x2){PB1, PB1};
  e = e * c + (f32x2){PB0, PB0};
  return e;
}

// ---------------- kernel 0: bucket-sort indices by target ----------------
// pi: sorted-pos -> original row; tps: t' = t + 10*sign(t) in sorted order
__global__ __launch_bounds__(1024) void sort_kernel(
    const float* __restrict__ targets,
    int* __restrict__ pi, float* __restrict__ tps) {
  __shared__ int hist[NBUCK];
  __shared__ int scanb[NBUCK];
  __shared__ float tloc[NROWS];
  const int tid = threadIdx.x;
  hist[tid] = 0;
  __syncthreads();
  #pragma unroll
  for (int r = 0; r < NROWS / 1024; ++r) {
    float t = targets[r * 1024 + tid];
    int b = (int)((t + 1.0f) * (NBUCK / 2));
    b = min(max(b, 0), NBUCK - 1);
    atomicAdd(&hist[b], 1);
  }
  __syncthreads();
  int own = hist[tid];
  scanb[tid] = own;
  __syncthreads();
  for (int d = 1; d < NBUCK; d <<= 1) {   // inclusive Hillis-Steele scan
    int nv = scanb[tid];
    if (tid >= d) nv += scanb[tid - d];
    __syncthreads();
    scanb[tid] = nv;
    __syncthreads();
  }
  hist[tid] = scanb[tid] - own;           // exclusive offset, reused as cursor
  __syncthreads();
  #pragma unroll
  for (int r = 0; r < NROWS / 1024; ++r) {
    int i = r * 1024 + tid;
    float t = targets[i];
    int b = (int)((t + 1.0f) * (NBUCK / 2));
    b = min(max(b, 0), NBUCK - 1);
    int pos = atomicAdd(&hist[b], 1);
    pi[pos] = i;
    tloc[pos] = t + (t > 0.0f ? 10.0f : -10.0f);
  }
  __syncthreads();
  #pragma unroll
  for (int r = 0; r < NROWS / 1024; ++r) {
    int i = r * 1024 + tid;
    tps[i] = tloc[i];
  }
}

// ---------------- kernel 1: gather-normalize into SORTED order ----------------
// f1b[r] = normalize(f1[pi[r]]) as bf16; same for f2b. Also zeroes out[0].
__global__ __launch_bounds__(256) void norm_kernel(
    const float* __restrict__ f1, const float* __restrict__ f2,
    const int* __restrict__ pi,
    __hip_bfloat16* __restrict__ f1b, __hip_bfloat16* __restrict__ f2b,
    float* __restrict__ out) {
  if (blockIdx.x == 0 && threadIdx.x == 0) out[0] = 0.0f;
  int t = threadIdx.x;
  int rloc = t >> 5;                 // 0..7
  int l = t & 31;
  int b = blockIdx.x;                // 0..2047
  int half = (b >= NROWS / 8) ? 1 : 0;
  int row = (b - half * (NROWS / 8)) * 8 + rloc;   // sorted position
  int srow = pi[row];                               // original row
  const float* src = half ? f2 : f1;
  __hip_bfloat16* dst = half ? f2b : f1b;

  float4 v = ((const float4*)src)[srow * (DDIM / 4) + l];
  float s = v.x * v.x + v.y * v.y + v.z * v.z + v.w * v.w;
  #pragma unroll
  for (int off = 1; off < 32; off <<= 1) s += __shfl_xor(s, off, 64);
  float inv = 1.0f / fmaxf(sqrtf(s), 1e-12f);
  __hip_bfloat16 hv[4];
  hv[0] = __float2bfloat16(v.x * inv);
  hv[1] = __float2bfloat16(v.y * inv);
  hv[2] = __float2bfloat16(v.z * inv);
  hv[3] = __float2bfloat16(v.w * inv);
  *(ushort4*)&dst[(size_t)row * DDIM + l * 4] = *(ushort4*)hv;
}

// ---------------- kernel 2: MFMA cos grid (sorted data), classified epilogue ----------------
// partials[(row*JCHUNKS + chunk)*4 + {Z, Zp, Cp, Np}], rows in sorted space
__global__ __launch_bounds__(256, 4) void stats_kernel(
    const __hip_bfloat16* __restrict__ f1b,
    const __hip_bfloat16* __restrict__ f2b,
    const float* __restrict__ tps,
    float* __restrict__ partials) {
  __shared__ __align__(16) char lds0[STAGE_COLS * 256];   // 16 KB
  __shared__ __align__(16) char lds1[STAGE_COLS * 256];   // 16 KB
  __shared__ __align__(16) float tsh[JPER];               // 2 KB (t', sorted chunk)

  const int chunk = blockIdx.y;
  const int i0 = blockIdx.x * ROWS_PER_BLOCK;
  const int w    = threadIdx.x >> 6;
  const int lane = threadIdx.x & 63;
  const int p15  = lane & 15;
  const int rl4  = lane >> 4;
  const int rbase = i0 + w * 32;

  // ---- A fragments resident for whole sweep (contiguous sorted rows) ----
  bf16x8 afrag[2][4];
  #pragma unroll
  for (int rs = 0; rs < 2; ++rs) {
    const __hip_bfloat16* arow =
        &f1b[(size_t)(rbase + rs * 16 + p15) * DDIM + rl4 * 8];
    #pragma unroll
    for (int ks = 0; ks < 4; ++ks)
      afrag[rs][ks] = *(const bf16x8*)(arow + ks * 32);
  }

  // lane's C rows: comp0 = quad*4+rr, comp1 = 16+quad*4+rr
  f32x2 tip2[4];
  #pragma unroll
  for (int rr = 0; rr < 4; ++rr) {
    tip2[rr][0] = tps[rbase + rl4 * 4 + rr];
    tip2[rr][1] = tps[rbase + 16 + rl4 * 4 + rr];
  }
  // wave rows are a sorted contiguous range: endpoints bound them
  // (bucket sort is only ~0.002-exact within a bucket -> conservative margins below)
  const float twmin = tps[rbase];
  const float twmax = tps[rbase + 31];

  f32x2 Z2[4]  = {{0,0},{0,0},{0,0},{0,0}};
  f32x2 Zp2[4] = {{0,0},{0,0},{0,0},{0,0}};
  f32x2 Cp2[4] = {{0,0},{0,0},{0,0},{0,0}};
  f32x2 Np2[4] = {{0,0},{0,0},{0,0},{0,0}};
  float posTiles = 0.0f;

  const int jb0 = chunk * JPER;

  // ---- DMA source offsets (elements) within a 64-row stage block ----
  int srcoff[4];
  #pragma unroll
  for (int q = 0; q < 4; ++q) {
    int rloc = w * 16 + q * 4 + rl4;
    int c    = p15 ^ (q * 4 + rl4);
    srcoff[q] = rloc * DDIM + c * 8;
  }

  // prologue: DMA t' chunk (2 rounds) + B stage 0 -> lds0
  #pragma unroll
  for (int rnd = 0; rnd < 2; ++rnd)
    __builtin_amdgcn_global_load_lds(
        (const AS1 void*)(tps + jb0 + rnd * 256 + w * 64 + lane),
        (AS3 void*)(&tsh[rnd * 256 + w * 64]), 4, 0, 0);
  {
    const __hip_bfloat16* gstage = f2b + (size_t)jb0 * DDIM;
    char* lbase = &lds0[w * 4096];
    #pragma unroll
    for (int q = 0; q < 4; ++q)
      __builtin_amdgcn_global_load_lds((const AS1 void*)(gstage + srcoff[q]),
                                       (AS3 void*)(lbase + q * 1024), 16, 0, 0);
  }

  for (int s = 0; s < NSTAGES; ++s) {
    __syncthreads();   // stage-s DMA complete; other buffer free

    if (s + 1 < NSTAGES) {
      const __hip_bfloat16* gstage = f2b + (size_t)(jb0 + (s + 1) * STAGE_COLS) * DDIM;
      char* lbase = ((s + 1) & 1) ? &lds1[w * 4096] : &lds0[w * 4096];
      #pragma unroll
      for (int q = 0; q < 4; ++q)
        __builtin_amdgcn_global_load_lds((const AS1 void*)(gstage + srcoff[q]),
                                         (AS3 void*)(lbase + q * 1024), 16, 0, 0);
    }

    const char* lb = (s & 1) ? lds1 : lds0;
    #pragma unroll
    for (int ct = 0; ct < 4; ++ct) {
      const int rloc = ct * 16 + p15;
      bf16x8 bfrag[4];
      #pragma unroll
      for (int ks = 0; ks < 4; ++ks)
        bfrag[ks] = *(const bf16x8*)(lb + rloc * 256 + (((rl4 + ks * 4) ^ p15) << 4));

      f32x4 acc0 = {0.f, 0.f, 0.f, 0.f};
      f32x4 acc1 = {0.f, 0.f, 0.f, 0.f};
      #pragma unroll
      for (int ks = 0; ks < 4; ++ks) {
        acc0 = __builtin_amdgcn_mfma_f32_16x16x32_bf16(afrag[0][ks], bfrag[ks], acc0, 0, 0, 0);
        acc1 = __builtin_amdgcn_mfma_f32_16x16x32_bf16(afrag[1][ks], bfrag[ks], acc1, 0, 0, 0);
      }

      // tile t' bounds from endpoints of the sorted 16-col group
      const int tb = s * STAGE_COLS + ct * 16;
      float jmn = tsh[tb], jmx = tsh[tb + 15];
      int uneg = __builtin_amdgcn_readfirstlane(
          ((jmn - twmax > 0.105f) || (twmin - jmx > 0.105f)) ? 1 : 0);
      int upos = __builtin_amdgcn_readfirstlane(
          ((twmax - jmn <= 0.095f) && (jmx - twmin <= 0.095f)) ? 1 : 0);

      if (uneg) {
        #pragma unroll
        for (int rr = 0; rr < 4; ++rr) {
          f32x2 c2 = {acc0[rr], acc1[rr]};
          Z2[rr] += expcm1(c2);
        }
      } else if (upos) {
        posTiles += 1.0f;
        #pragma unroll
        for (int rr = 0; rr < 4; ++rr) {
          f32x2 c2 = {acc0[rr], acc1[rr]};
          f32x2 e2 = expcm1(c2);
          Z2[rr]  += e2;
          Zp2[rr] += e2;
          Cp2[rr] += c2;
        }
      } else {
        float tj = tsh[tb + p15];
        f32x2 tj2 = {tj, tj};
        #pragma unroll
        for (int rr = 0; rr < 4; ++rr) {
          f32x2 c2 = {acc0[rr], acc1[rr]};
          f32x2 d2 = tip2[rr] - tj2;
          bool q0 = __builtin_fabsf(d2[0]) <= 0.1f;
          bool q1 = __builtin_fabsf(d2[1]) <= 0.1f;
          f32x2 m2 = {q0 ? 1.0f : 0.0f, q1 ? 1.0f : 0.0f};
          f32x2 e2 = expcm1(c2);
          Z2[rr]  += e2;
          Zp2[rr] += m2 * e2;
          Cp2[rr] += m2 * c2;
          Np2[rr] += m2;
        }
      }
    }
  }

  // uniform-pos tiles: every lane's column was a hit for all its rows
  #pragma unroll
  for (int rr = 0; rr < 4; ++rr)
    Np2[rr] += (f32x2){posTiles, posTiles};

  // reduce over the 16 lanes (p15) sharing each row
  #pragma unroll
  for (int rr = 0; rr < 4; ++rr) {
    for (int off = 1; off < 16; off <<= 1) {
      Z2[rr][0]  += __shfl_xor(Z2[rr][0],  off, 64);
      Z2[rr][1]  += __shfl_xor(Z2[rr][1],  off, 64);
      Zp2[rr][0] += __shfl_xor(Zp2[rr][0], off, 64);
      Zp2[rr][1] += __shfl_xor(Zp2[rr][1], off, 64);
      Cp2[rr][0] += __shfl_xor(Cp2[rr][0], off, 64);
      Cp2[rr][1] += __shfl_xor(Cp2[rr][1], off, 64);
      Np2[rr][0] += __shfl_xor(Np2[rr][0], off, 64);
      Np2[rr][1] += __shfl_xor(Np2[rr][1], off, 64);
    }
  }
  if (p15 == 0) {
    #pragma unroll
    for (int rs = 0; rs < 2; ++rs)
      #pragma unroll
      for (int rr = 0; rr < 4; ++rr) {
        size_t row = rbase + rs * 16 + rl4 * 4 + rr;
        f32x4 st = {Z2[rr][rs], Zp2[rr][rs], Cp2[rr][rs], Np2[rr][rs]};
        *(f32x4*)&partials[((size_t)row * JCHUNKS + chunk) * 4] = st;
      }
  }
}

// ---------------- kernel 3: per-row loss + global mean (atomic) ----------------
__global__ void finalize_rows(const float* __restrict__ partials,
                              float* __restrict__ out) {
  int r = blockIdx.x * 256 + threadIdx.x;   // grid 32 x 256
  float Z = 0, Zp = 0, Cp = 0, Np = 0;
  for (int ch = 0; ch < JCHUNKS; ++ch) {
    float4 p = *(const float4*)&partials[((size_t)r * JCHUNKS + ch) * 4];
    Z += p.x; Zp += p.y; Cp += p.z; Np += p.w;
  }
  float Zn = Z - Zp;
  float nn = (float)NROWS - Np;
  float spos = (1.0f + logf(Z)) - Cp / Np;
  float sneg = Zn / Z - nn * 1e-10f;
  float per_row = spos + sneg / nn;

  float v = per_row;
  for (int off = 32; off; off >>= 1) v += __shfl_xor(v, off, 64);
  __shared__ float wsum[4];
  int lane = threadIdx.x & 63, wid = threadIdx.x >> 6;
  if (lane == 0) wsum[wid] = v;
  __syncthreads();
  if (threadIdx.x == 0)
    atomicAdd(out, (wsum[0] + wsum[1] + wsum[2] + wsum[3]) * (1.0f / (float)NROWS));
}

// ---------------- launch ----------------
extern "C" void kernel_launch(void* const* d_in, const int* in_sizes, int n_in,
                              void* d_out, int out_size, void* d_ws, size_t ws_size,
                              hipStream_t stream) {
  const float* f1  = (const float*)d_in[0];
  const float* f2  = (const float*)d_in[1];
  const float* tgt = (const float*)d_in[2];
  float* out = (float*)d_out;

  char* ws = (char*)d_ws;
  __hip_bfloat16* f1b = (__hip_bfloat16*)ws;                          // 2 MB
  __hip_bfloat16* f2b = (__hip_bfloat16*)(ws + (size_t)NROWS * DDIM * 2);
  float* partials = (float*)(ws + (size_t)NROWS * DDIM * 4);          // 2 MB
  int*   pi  = (int*)((char*)partials + (size_t)NROWS * JCHUNKS * 16);
  float* tps = (float*)((char*)pi + NROWS * 4);

  sort_kernel<<<1, 1024, 0, stream>>>(tgt, pi, tps);
  norm_kernel<<<2 * (NROWS / 8), 256, 0, stream>>>(f1, f2, pi, f1b, f2b, out);
  dim3 g2(GRIDX, JCHUNKS);
  stats_kernel<<<g2, 256, 0, stream>>>(f1b, f2b, tps, partials);
  finalize_rows<<<NROWS / 256, 256, 0, stream>>>(partials, out);
}